// Round 1
// baseline (3331.176 us; speedup 1.0000x reference)
//
#include <hip/hip_runtime.h>
#include <hip/hip_bf16.h>
#include <stdint.h>

// CustomLSTMForecast: B=512, T=256, I=256, H=512
// Persistent-weight LSTM: grid = 256 WGs (8 batch-chunks x 32 col-groups),
// block = 256 threads (4 waves). Each WG owns batch rows [chunk*64,+64),
// h-cols [jb*16,+16) => gate rows {n*512 + jb*16 + c : n=0..3}.
// Weights stay resident: h-part B-fragments in LDS (64 KiB), x-part in VGPRs.
// Per-chunk flag barrier (agent scope) between timesteps.

#define B_SZ 512
#define T_SZ 256
#define I_SZ 256
#define H_SZ 512
#define K_SZ 768  // H + I

typedef float  f32x4  __attribute__((ext_vector_type(4)));
typedef __bf16 bf16x8 __attribute__((ext_vector_type(8)));

__device__ __forceinline__ float fast_sigmoid(float v) {
  return __builtin_amdgcn_rcpf(1.0f + __expf(-v));
}
__device__ __forceinline__ float fast_tanh(float v) {
  // tanh(v) = 1 - 2/(exp(2v)+1); inf-safe: exp->inf => rcp->0 => 1
  return 1.0f - 2.0f * __builtin_amdgcn_rcpf(1.0f + __expf(2.0f * v));
}

__global__ __launch_bounds__(256, 1)
void lstm_persist(const float* __restrict__ x,
                  const float* __restrict__ Ww,
                  const float* __restrict__ Wb,
                  __bf16* __restrict__ hbuf,        // 2 * B * H bf16 (dbuf)
                  float* __restrict__ hf32,         // B * H final h (f32)
                  unsigned int* __restrict__ flags) // 8 chunks * 32 WGs
{
  // Pre-packed MFMA B-fragments for the h-part weights:
  // index c = kt*4 + nt (kt in [0,16), nt = gate in [0,4)), then lane.
  __shared__ bf16x8 bh[64 * 64];  // 64 KiB

  const int wg    = blockIdx.x;
  const int chunk = wg & 7;   // batch chunk of 64 rows (XCD-affine)
  const int jb    = wg >> 3;  // h-col group of 16, 0..31
  const int tid   = threadIdx.x;
  const int wv    = tid >> 6; // wave = m-tile (16 batch rows)
  const int ln    = tid & 63;
  const int l16   = ln & 15;
  const int lhi   = ln >> 4;  // 0..3

  const int colW = jb * 16 + l16;  // this lane's h-column (B-frag col / D col)

  // ---- stage h-part weight fragments into LDS (k = 0..511) ----
  for (int c = wv; c < 64; c += 4) {
    const int kt = c >> 2;
    const int nt = c & 3;
    const int k0 = kt * 32 + lhi * 8;
    const int g  = nt * 512 + colW;           // gate row in W_w
    const float* wr = Ww + (size_t)g * K_SZ + k0;
    const float4 w0 = *(const float4*)(wr);
    const float4 w1 = *(const float4*)(wr + 4);
    bf16x8 v;
    v[0]=(__bf16)w0.x; v[1]=(__bf16)w0.y; v[2]=(__bf16)w0.z; v[3]=(__bf16)w0.w;
    v[4]=(__bf16)w1.x; v[5]=(__bf16)w1.y; v[6]=(__bf16)w1.z; v[7]=(__bf16)w1.w;
    bh[c * 64 + ln] = v;
  }

  // ---- x-part weight fragments into registers (k = 512..767) ----
  bf16x8 bx[8][4];
#pragma unroll
  for (int kt = 0; kt < 8; ++kt) {
#pragma unroll
    for (int nt = 0; nt < 4; ++nt) {
      const int k0 = 512 + kt * 32 + lhi * 8;
      const int g  = nt * 512 + colW;
      const float* wr = Ww + (size_t)g * K_SZ + k0;
      const float4 w0 = *(const float4*)(wr);
      const float4 w1 = *(const float4*)(wr + 4);
      bf16x8 v;
      v[0]=(__bf16)w0.x; v[1]=(__bf16)w0.y; v[2]=(__bf16)w0.z; v[3]=(__bf16)w0.w;
      v[4]=(__bf16)w1.x; v[5]=(__bf16)w1.y; v[6]=(__bf16)w1.z; v[7]=(__bf16)w1.w;
      bx[kt][nt] = v;
    }
  }

  const float bias0 = Wb[0 * 512 + colW];
  const float bias1 = Wb[1 * 512 + colW];
  const float bias2 = Wb[2 * 512 + colW];
  const float bias3 = Wb[3 * 512 + colW];

  __syncthreads();

  // cell state: element (rowD + r, colW) per lane, r = 0..3
  float cst[4] = {0.f, 0.f, 0.f, 0.f};

  const int rowA = chunk * 64 + wv * 16 + l16;       // A-fragment row
  const int rowD = chunk * 64 + wv * 16 + lhi * 4;   // D rows base (+r)
  const float* xrow = x + (size_t)rowA * T_SZ * I_SZ + lhi * 8;
  unsigned int* chunkFlags = flags + chunk * 32;

  for (int t = 0; t < T_SZ; ++t) {
    if (t > 0) {
      // wait until all 32 WGs of this chunk published h_t
      if (wv == 0) {
        if (ln < 32) {
          while (__hip_atomic_load(&chunkFlags[ln], __ATOMIC_RELAXED,
                                   __HIP_MEMORY_SCOPE_AGENT) < (unsigned)t) { }
        }
        __builtin_amdgcn_fence(__ATOMIC_ACQUIRE, "agent");
      }
      __syncthreads();
    }

    const __bf16* hin  = hbuf + (size_t)(t & 1) * (B_SZ * H_SZ);
    __bf16*       hout = hbuf + (size_t)((t + 1) & 1) * (B_SZ * H_SZ);

    f32x4 acc0 = {0.f,0.f,0.f,0.f}, acc1 = {0.f,0.f,0.f,0.f};
    f32x4 acc2 = {0.f,0.f,0.f,0.f}, acc3 = {0.f,0.f,0.f,0.f};

    // h-part: K = 0..511 from h_t (bf16, row-major H)
    const bf16x8* hrow = (const bf16x8*)(hin + (size_t)rowA * H_SZ);
#pragma unroll
    for (int kt = 0; kt < 16; ++kt) {
      const bf16x8 a = hrow[kt * 4 + lhi];
      acc0 = __builtin_amdgcn_mfma_f32_16x16x32_bf16(a, bh[(kt*4+0)*64 + ln], acc0, 0, 0, 0);
      acc1 = __builtin_amdgcn_mfma_f32_16x16x32_bf16(a, bh[(kt*4+1)*64 + ln], acc1, 0, 0, 0);
      acc2 = __builtin_amdgcn_mfma_f32_16x16x32_bf16(a, bh[(kt*4+2)*64 + ln], acc2, 0, 0, 0);
      acc3 = __builtin_amdgcn_mfma_f32_16x16x32_bf16(a, bh[(kt*4+3)*64 + ln], acc3, 0, 0, 0);
    }

    // x-part: K = 512..767 from x[b, t, :] (f32 -> bf16 on the fly)
    const float* xr = xrow + (size_t)t * I_SZ;
#pragma unroll
    for (int kt = 0; kt < 8; ++kt) {
      const float4 x0 = *(const float4*)(xr + kt * 32);
      const float4 x1 = *(const float4*)(xr + kt * 32 + 4);
      bf16x8 a;
      a[0]=(__bf16)x0.x; a[1]=(__bf16)x0.y; a[2]=(__bf16)x0.z; a[3]=(__bf16)x0.w;
      a[4]=(__bf16)x1.x; a[5]=(__bf16)x1.y; a[6]=(__bf16)x1.z; a[7]=(__bf16)x1.w;
      acc0 = __builtin_amdgcn_mfma_f32_16x16x32_bf16(a, bx[kt][0], acc0, 0, 0, 0);
      acc1 = __builtin_amdgcn_mfma_f32_16x16x32_bf16(a, bx[kt][1], acc1, 0, 0, 0);
      acc2 = __builtin_amdgcn_mfma_f32_16x16x32_bf16(a, bx[kt][2], acc2, 0, 0, 0);
      acc3 = __builtin_amdgcn_mfma_f32_16x16x32_bf16(a, bx[kt][3], acc3, 0, 0, 0);
    }

    // elementwise LSTM: acc{0,1,2,3}[r] are f/i/o/chat for the SAME (row,col)
#pragma unroll
    for (int r = 0; r < 4; ++r) {
      const float fg = fast_sigmoid(acc0[r] + bias0);
      const float ig = fast_sigmoid(acc1[r] + bias1);
      const float og = fast_sigmoid(acc2[r] + bias2);
      const float gg = fast_tanh(acc3[r] + bias3);
      const float cn = fg * cst[r] + ig * gg;
      cst[r] = cn;
      const float hn = og * fast_tanh(cn);
      const int row = rowD + r;
      hout[(size_t)row * H_SZ + colW] = (__bf16)hn;
      if (t == T_SZ - 1) hf32[(size_t)row * H_SZ + colW] = hn;
    }

    __syncthreads();  // drains all waves' stores (vmcnt(0) before s_barrier)
    if (tid == 0) {
      __builtin_amdgcn_fence(__ATOMIC_RELEASE, "agent");  // wbl2: publish h_{t+1}
      __hip_atomic_store(&chunkFlags[jb], (unsigned)(t + 1), __ATOMIC_RELAXED,
                         __HIP_MEMORY_SCOPE_AGENT);
    }
  }
}

// out[b] = dot(h_T[b], fc_w) + fc_b
__global__ __launch_bounds__(256)
void fc_head(const float* __restrict__ hf32, const float* __restrict__ fcw,
             const float* __restrict__ fcb, float* __restrict__ out)
{
  const int b = blockIdx.x * 256 + threadIdx.x;
  if (b >= B_SZ) return;
  const float4* hp = (const float4*)(hf32 + (size_t)b * H_SZ);
  const float4* wp = (const float4*)fcw;
  float s = 0.f;
#pragma unroll 8
  for (int j = 0; j < H_SZ / 4; ++j) {
    const float4 h = hp[j];
    const float4 w = wp[j];
    s += h.x * w.x + h.y * w.y + h.z * w.z + h.w * w.w;
  }
  out[b] = s + fcb[0];
}

extern "C" void kernel_launch(void* const* d_in, const int* in_sizes, int n_in,
                              void* d_out, int out_size, void* d_ws, size_t ws_size,
                              hipStream_t stream) {
  const float* x   = (const float*)d_in[0];  // (B, T, I) f32
  const float* Ww  = (const float*)d_in[1];  // (2048, 768) f32
  const float* Wb  = (const float*)d_in[2];  // (2048,) f32
  const float* fcw = (const float*)d_in[3];  // (1, 512) f32
  const float* fcb = (const float*)d_in[4];  // (1,) f32
  float* out = (float*)d_out;                // (B, 1) f32

  char* ws = (char*)d_ws;
  // layout: [flags 4KiB][h0 512KiB][h1 512KiB][hf32 1MiB]
  unsigned int* flags = (unsigned int*)ws;
  __bf16* hbuf = (__bf16*)(ws + 4096);
  float*  hf32 = (float*)(ws + 4096 + (size_t)2 * B_SZ * H_SZ * sizeof(__bf16));

  // zero flags + h0 (single contiguous memset); h1/hf32 are fully overwritten
  hipMemsetAsync(ws, 0, 4096 + (size_t)B_SZ * H_SZ * sizeof(__bf16), stream);

  lstm_persist<<<256, 256, 0, stream>>>(x, Ww, Wb, hbuf, hf32, flags);
  fc_head<<<2, 256, 0, stream>>>(hf32, fcw, fcb, out);
}

// Round 2
// 1834.500 us; speedup vs baseline: 1.8158x; 1.8158x over previous
//
#include <hip/hip_runtime.h>
#include <hip/hip_bf16.h>
#include <stdint.h>

// CustomLSTMForecast: B=512, T=256, I=256, H=512
// Persistent-weight LSTM, fence-free sync:
//   grid = 256 WGs (8 batch-chunks x 32 col-groups), block = 256 (4 waves).
//   WG owns batch rows [chunk*64,+64), h-cols [jb*16,+16).
//   ALL weights (96 KiB bf16) LDS-resident. h exchanged via L3 (sc0 sc1
//   bypass loads/stores) + per-(chunk,wave) monotonic counters — no agent
//   fences, L2 never invalidated.

#define B_SZ 512
#define T_SZ 256
#define I_SZ 256
#define H_SZ 512
#define K_SZ 768           // H + I
#define BH   (B_SZ * H_SZ)

typedef float  f32x4  __attribute__((ext_vector_type(4)));
typedef __bf16 bf16x8 __attribute__((ext_vector_type(8)));

__device__ __forceinline__ float fast_sigmoid(float v) {
  return __builtin_amdgcn_rcpf(1.0f + __expf(-v));
}
__device__ __forceinline__ float fast_tanh(float v) {
  return 1.0f - 2.0f * __builtin_amdgcn_rcpf(1.0f + __expf(2.0f * v));
}

// L3-coherent 16B load (bypass L1+L2): dst <- [hsrc + imm]
#define HLOAD(dst, off) \
  asm volatile("global_load_dwordx4 %0, %1, off offset:" off " sc0 sc1" \
               : "=v"(dst) : "v"(hsrc) : "memory")
// L3-coherent 2B store: [hdst + imm] <- low16(val)
#define HSTORE(off, val) \
  asm volatile("global_store_short %0, %1, off offset:" off " sc0 sc1" \
               :: "v"(hdst), "v"(val) : "memory")

__global__ __launch_bounds__(256, 1)
void lstm_persist(const float* __restrict__ x,
                  const float* __restrict__ Ww,
                  const float* __restrict__ Wb,
                  __bf16* __restrict__ hbuf,        // 2 * B * H bf16 (dbuf)
                  float* __restrict__ hf32,         // B * H final h (f32)
                  unsigned int* __restrict__ flags) // 8 chunks * 4 waves cnts
{
  // B-fragments for ALL weights: c = kt*4 + nt, kt in [0,24) covers
  // k = kt*32 (h-part kt<16, x-part kt>=16 since 16*32 == 512 == H).
  __shared__ bf16x8 bw[96 * 64];  // 96 KiB

  const int wg    = blockIdx.x;
  const int chunk = wg & 7;   // batch chunk of 64 rows (XCD-affine)
  const int jb    = wg >> 3;  // h-col group of 16, 0..31
  const int tid   = threadIdx.x;
  const int wv    = tid >> 6; // wave = m-tile (16 batch rows)
  const int ln    = tid & 63;
  const int l16   = ln & 15;
  const int lhi   = ln >> 4;  // 0..3

  const int colW = jb * 16 + l16;  // this lane's h-column

  // ---- stage all weight fragments into LDS ----
  for (int c = wv; c < 96; c += 4) {
    const int kt = c >> 2;
    const int nt = c & 3;
    const int k0 = kt * 32 + lhi * 8;
    const int g  = nt * 512 + colW;           // gate row in W_w
    const float* wr = Ww + (size_t)g * K_SZ + k0;
    const float4 w0 = *(const float4*)(wr);
    const float4 w1 = *(const float4*)(wr + 4);
    bf16x8 v;
    v[0]=(__bf16)w0.x; v[1]=(__bf16)w0.y; v[2]=(__bf16)w0.z; v[3]=(__bf16)w0.w;
    v[4]=(__bf16)w1.x; v[5]=(__bf16)w1.y; v[6]=(__bf16)w1.z; v[7]=(__bf16)w1.w;
    bw[c * 64 + ln] = v;
  }

  const float bias0 = Wb[0 * 512 + colW];
  const float bias1 = Wb[1 * 512 + colW];
  const float bias2 = Wb[2 * 512 + colW];
  const float bias3 = Wb[3 * 512 + colW];

  __syncthreads();  // weights ready (only barrier in the kernel)

  float cst[4] = {0.f, 0.f, 0.f, 0.f};

  const int rowA = chunk * 64 + wv * 16 + l16;       // A-fragment row
  const int rowD = chunk * 64 + wv * 16 + lhi * 4;   // D rows base (+r)
  const float* xrow = x + (size_t)rowA * T_SZ * I_SZ + lhi * 8;
  unsigned int* cnt = flags + (chunk * 4 + wv) * 32; // 128B-spaced counter

  // x prefetch registers (f32, converted at consume time)
  float4 xp0[8], xp1[8];
  {
    const float* xr = xrow;  // t = 0
#pragma unroll
    for (int kt = 0; kt < 8; ++kt) {
      xp0[kt] = *(const float4*)(xr + kt * 32);
      xp1[kt] = *(const float4*)(xr + kt * 32 + 4);
    }
  }

  bf16x8 hf[16];

  for (int t = 0; t < T_SZ; ++t) {
    // ---- wait for h_t, issue h-fragment loads (L3 bypass) ----
    if (t > 0) {
      const unsigned target = 32u * (unsigned)t;
      while (__hip_atomic_load(cnt, __ATOMIC_RELAXED,
                               __HIP_MEMORY_SCOPE_AGENT) < target) { }
      const __bf16* hsrc = hbuf + (size_t)(t & 1) * BH
                                + (size_t)rowA * H_SZ + lhi * 8;
      HLOAD(hf[0],  "0");   HLOAD(hf[1],  "64");  HLOAD(hf[2],  "128");
      HLOAD(hf[3],  "192"); HLOAD(hf[4],  "256"); HLOAD(hf[5],  "320");
      HLOAD(hf[6],  "384"); HLOAD(hf[7],  "448"); HLOAD(hf[8],  "512");
      HLOAD(hf[9],  "576"); HLOAD(hf[10], "640"); HLOAD(hf[11], "704");
      HLOAD(hf[12], "768"); HLOAD(hf[13], "832"); HLOAD(hf[14], "896");
      HLOAD(hf[15], "960");
    }

    f32x4 acc0 = {0.f,0.f,0.f,0.f}, acc1 = {0.f,0.f,0.f,0.f};
    f32x4 acc2 = {0.f,0.f,0.f,0.f}, acc3 = {0.f,0.f,0.f,0.f};

    // ---- x-part (independent of h) overlaps the h-load latency ----
#pragma unroll
    for (int kt = 0; kt < 8; ++kt) {
      bf16x8 a;
      a[0]=(__bf16)xp0[kt].x; a[1]=(__bf16)xp0[kt].y;
      a[2]=(__bf16)xp0[kt].z; a[3]=(__bf16)xp0[kt].w;
      a[4]=(__bf16)xp1[kt].x; a[5]=(__bf16)xp1[kt].y;
      a[6]=(__bf16)xp1[kt].z; a[7]=(__bf16)xp1[kt].w;
      const int cb = (16 + kt) * 4;
      acc0 = __builtin_amdgcn_mfma_f32_16x16x32_bf16(a, bw[(cb+0)*64 + ln], acc0, 0, 0, 0);
      acc1 = __builtin_amdgcn_mfma_f32_16x16x32_bf16(a, bw[(cb+1)*64 + ln], acc1, 0, 0, 0);
      acc2 = __builtin_amdgcn_mfma_f32_16x16x32_bf16(a, bw[(cb+2)*64 + ln], acc2, 0, 0, 0);
      acc3 = __builtin_amdgcn_mfma_f32_16x16x32_bf16(a, bw[(cb+3)*64 + ln], acc3, 0, 0, 0);
    }

    // ---- h-part ----
    if (t > 0) {
      asm volatile("s_waitcnt vmcnt(0)" ::: "memory");
      __builtin_amdgcn_sched_barrier(0);
#pragma unroll
      for (int kt = 0; kt < 16; ++kt) {
        const int cb = kt * 4;
        acc0 = __builtin_amdgcn_mfma_f32_16x16x32_bf16(hf[kt], bw[(cb+0)*64 + ln], acc0, 0, 0, 0);
        acc1 = __builtin_amdgcn_mfma_f32_16x16x32_bf16(hf[kt], bw[(cb+1)*64 + ln], acc1, 0, 0, 0);
        acc2 = __builtin_amdgcn_mfma_f32_16x16x32_bf16(hf[kt], bw[(cb+2)*64 + ln], acc2, 0, 0, 0);
        acc3 = __builtin_amdgcn_mfma_f32_16x16x32_bf16(hf[kt], bw[(cb+3)*64 + ln], acc3, 0, 0, 0);
      }
    }

    // ---- elementwise LSTM (f/i/o/chat per lane, same (row,col)) ----
    float hnv[4];
#pragma unroll
    for (int r = 0; r < 4; ++r) {
      const float fg = fast_sigmoid(acc0[r] + bias0);
      const float ig = fast_sigmoid(acc1[r] + bias1);
      const float og = fast_sigmoid(acc2[r] + bias2);
      const float gg = fast_tanh(acc3[r] + bias3);
      const float cn = fg * cst[r] + ig * gg;
      cst[r] = cn;
      hnv[r] = og * fast_tanh(cn);
    }

    if (t < T_SZ - 1) {
      // publish h_{t+1} through L3, then bump this row-block's counter
      __bf16* hdst = hbuf + (size_t)((t + 1) & 1) * BH
                          + (size_t)rowD * H_SZ + colW;
      const unsigned u0 = __builtin_bit_cast(unsigned short, (__bf16)hnv[0]);
      const unsigned u1 = __builtin_bit_cast(unsigned short, (__bf16)hnv[1]);
      const unsigned u2 = __builtin_bit_cast(unsigned short, (__bf16)hnv[2]);
      const unsigned u3 = __builtin_bit_cast(unsigned short, (__bf16)hnv[3]);
      HSTORE("0",    u0);
      HSTORE("1024", u1);
      HSTORE("2048", u2);
      HSTORE("3072", u3);
      asm volatile("s_waitcnt vmcnt(0)" ::: "memory");  // stores at L3
      if (ln == 0)
        __hip_atomic_fetch_add(cnt, 1u, __ATOMIC_RELAXED,
                               __HIP_MEMORY_SCOPE_AGENT);
      // prefetch x for t+1 (normal cached loads; hides under the spin)
      const float* xr = xrow + (size_t)(t + 1) * I_SZ;
#pragma unroll
      for (int kt = 0; kt < 8; ++kt) {
        xp0[kt] = *(const float4*)(xr + kt * 32);
        xp1[kt] = *(const float4*)(xr + kt * 32 + 4);
      }
    } else {
      // final h -> f32 for the fc head (normal stores; kernel-end release)
#pragma unroll
      for (int r = 0; r < 4; ++r)
        hf32[(size_t)(rowD + r) * H_SZ + colW] = hnv[r];
    }
  }
}

// out[b] = dot(h_T[b], fc_w) + fc_b
__global__ __launch_bounds__(256)
void fc_head(const float* __restrict__ hf32, const float* __restrict__ fcw,
             const float* __restrict__ fcb, float* __restrict__ out)
{
  const int b = blockIdx.x * 256 + threadIdx.x;
  if (b >= B_SZ) return;
  const float4* hp = (const float4*)(hf32 + (size_t)b * H_SZ);
  const float4* wp = (const float4*)fcw;
  float s = 0.f;
#pragma unroll 8
  for (int j = 0; j < H_SZ / 4; ++j) {
    const float4 h = hp[j];
    const float4 w = wp[j];
    s += h.x * w.x + h.y * w.y + h.z * w.z + h.w * w.w;
  }
  out[b] = s + fcb[0];
}

extern "C" void kernel_launch(void* const* d_in, const int* in_sizes, int n_in,
                              void* d_out, int out_size, void* d_ws, size_t ws_size,
                              hipStream_t stream) {
  const float* x   = (const float*)d_in[0];  // (B, T, I) f32
  const float* Ww  = (const float*)d_in[1];  // (2048, 768) f32
  const float* Wb  = (const float*)d_in[2];  // (2048,) f32
  const float* fcw = (const float*)d_in[3];  // (1, 512) f32
  const float* fcb = (const float*)d_in[4];  // (1,) f32
  float* out = (float*)d_out;                // (B, 1) f32

  char* ws = (char*)d_ws;
  // layout: [counters 4KiB][h0 512KiB][h1 512KiB][hf32 1MiB]
  unsigned int* flags = (unsigned int*)ws;
  __bf16* hbuf = (__bf16*)(ws + 4096);
  float*  hf32 = (float*)(ws + 4096 + (size_t)2 * BH * sizeof(__bf16));

  // zero the counters only (h0 is never read: h-part skipped at t=0)
  hipMemsetAsync(ws, 0, 4096, stream);

  lstm_persist<<<256, 256, 0, stream>>>(x, Ww, Wb, hbuf, hf32, flags);
  fc_head<<<2, 256, 0, stream>>>(hf32, fcw, fcb, out);
}